// Round 1
// baseline (303.936 us; speedup 1.0000x reference)
//
#include <hip/hip_runtime.h>
#include <hip/hip_bf16.h>
#include <cstdint>
#include <cstddef>

// ---- problem constants ----
constexpr int SEQ   = 4096;
constexpr int HIDN  = 2048;
constexpr int NHEAD = 8;
constexpr int NKVH  = 4;
constexpr int DH    = 256;
constexpr int NQR   = 6;
constexpr int NPROJ = 2624;      // 48 + 8 + 8 + 1536 + 512 + 512
constexpr int NPROJP= 2688;      // padded to /128
constexpr int WIN   = 1024;

typedef __attribute__((ext_vector_type(4))) float f32x4;
typedef __attribute__((ext_vector_type(8))) short bf16x8;
typedef unsigned short u16;

__device__ __forceinline__ u16 f2bf(float x) {
  union { float f; uint32_t u; } v; v.f = x;
  uint32_t r = v.u + 0x7fffu + ((v.u >> 16) & 1u);
  return (u16)(r >> 16);
}

// async global->LDS, 16B per lane, dest = wave-uniform base + lane*16 (linear)
__device__ __forceinline__ void gl_lds16(const u16* g, u16* l) {
  __builtin_amdgcn_global_load_lds(
      (const __attribute__((address_space(1))) uint32_t*)g,
      (__attribute__((address_space(3))) uint32_t*)l, 16, 0, 0);
}

// ---------------- f32 -> bf16 convert (vectorized x4) ----------------
__global__ __launch_bounds__(256) void k_cvt(const float* __restrict__ src,
                                             u16* __restrict__ dst, int n4) {
  int i = blockIdx.x * 256 + threadIdx.x;
  if (i >= n4) return;
  float4 v = ((const float4*)src)[i];
  ushort4 o; o.x = f2bf(v.x); o.y = f2bf(v.y); o.z = f2bf(v.z); o.w = f2bf(v.w);
  ((ushort4*)dst)[i] = o;
}

// ---------------- build concatenated projection weight (bf16, padded) ----------------
__global__ __launch_bounds__(256) void k_wcat(
    const float* __restrict__ waq, const float* __restrict__ wak,
    const float* __restrict__ wav, const float* __restrict__ wbq,
    const float* __restrict__ wbk, const float* __restrict__ wbv,
    u16* __restrict__ wcat) {
  const int r = blockIdx.x;            // 0..2687
  const int col0 = threadIdx.x * 8;    // 8 cols per thread
  u16* out = wcat + (size_t)r * HIDN + col0;
  const float* src = nullptr; int rr = 0;
  if      (r < 48)   { src = waq; rr = r; }
  else if (r < 56)   { src = wak; rr = r - 48; }
  else if (r < 64)   { src = wav; rr = r - 56; }
  else if (r < 1600) { src = wbq; rr = r - 64; }
  else if (r < 2112) { src = wbk; rr = r - 1600; }
  else if (r < 2624) { src = wbv; rr = r - 2112; }
  if (!src) {
    ushort4 z = {0,0,0,0}; ((ushort4*)out)[0] = z; ((ushort4*)out)[1] = z; return;
  }
  const float* s = src + (size_t)rr * HIDN + col0;
#pragma unroll
  for (int i = 0; i < 2; ++i) {
    float4 v = ((const float4*)s)[i];
    ushort4 o; o.x = f2bf(v.x); o.y = f2bf(v.y); o.z = f2bf(v.z); o.w = f2bf(v.w);
    ((ushort4*)out)[i] = o;
  }
}

// ---------------- bf16 GEMM: C(MxN) = A(MxK) @ B(NxK)^T, f32 out ----------------
// m97 structure: 128x128 tile, BK=32, 4 waves (2x2 of 64x64), global_load_lds w16,
// double-buffered LDS, chunk-XOR swizzle (stage pre-swizzles global src).
__global__ __launch_bounds__(256)
void k_gemm_bt(const u16* __restrict__ A, const u16* __restrict__ Bm,
               float* __restrict__ C, int M, int N, int K) {
  __shared__ u16 lA[2][128 * 32];
  __shared__ u16 lB[2][128 * 32];
  const int tid = threadIdx.x;
  const int wid = tid >> 6, lane = tid & 63;
  const int l15 = lane & 15, g = lane >> 4;
  const int m0 = blockIdx.y * 128, n0 = blockIdx.x * 128;
  const int wr = wid >> 1, wc = wid & 1;
  f32x4 acc[4][4];
#pragma unroll
  for (int m = 0; m < 4; ++m)
#pragma unroll
    for (int n = 0; n < 4; ++n) acc[m][n] = (f32x4){0.f,0.f,0.f,0.f};
  const int NT = K >> 5;

  auto stage = [&](int buf, int kt) {
    const int k0 = kt << 5;
#pragma unroll
    for (int i = 0; i < 2; ++i) {
      const int u = i * 256 + tid;          // 16B chunk id: row = u>>2, slot = u&3
      const int row = u >> 2, cs = u & 3;
      const int cc = cs ^ ((row >> 1) & 3); // logical chunk held in this slot
      gl_lds16(A  + (size_t)(m0 + row) * K + k0 + cc * 8, &lA[buf][(i*256 + wid*64) * 8]);
      gl_lds16(Bm + (size_t)(n0 + row) * K + k0 + cc * 8, &lB[buf][(i*256 + wid*64) * 8]);
    }
  };

  stage(0, 0);
  int cur = 0;
  for (int kt = 0; kt < NT; ++kt) {
    __syncthreads();                         // staged buf[cur] ready (vmcnt drain)
    if (kt + 1 < NT) stage(cur ^ 1, kt + 1);
    bf16x8 af[4], bfr[4];
#pragma unroll
    for (int m = 0; m < 4; ++m) {
      const int row = wr*64 + m*16 + l15;
      const int cc = g ^ ((row >> 1) & 3);
      af[m] = *(const bf16x8*)&lA[cur][row*32 + cc*8];
    }
#pragma unroll
    for (int n = 0; n < 4; ++n) {
      const int row = wc*64 + n*16 + l15;
      const int cc = g ^ ((row >> 1) & 3);
      bfr[n] = *(const bf16x8*)&lB[cur][row*32 + cc*8];
    }
#pragma unroll
    for (int m = 0; m < 4; ++m)
#pragma unroll
      for (int n = 0; n < 4; ++n)
        acc[m][n] = __builtin_amdgcn_mfma_f32_16x16x32_bf16(af[m], bfr[n], acc[m][n], 0, 0, 0);
    cur ^= 1;
  }
#pragma unroll
  for (int m = 0; m < 4; ++m)
#pragma unroll
    for (int n = 0; n < 4; ++n)
#pragma unroll
      for (int j = 0; j < 4; ++j) {
        const int row = m0 + wr*64 + m*16 + g*4 + j;   // C/D: row=(lane>>4)*4+reg
        const int col = n0 + wc*64 + n*16 + l15;       //      col=lane&15
        C[(size_t)row * N + col] = acc[m][n][j];
      }
}

// ---------------- RoPE + rank-contract + RMSNorm -> q,k,v (bf16) ----------------
__global__ __launch_bounds__(256)
void k_qkv(const float* __restrict__ Y, const float* __restrict__ cosT,
           const float* __restrict__ sinT, const float* __restrict__ qw,
           const float* __restrict__ kw, u16* __restrict__ q_s,
           u16* __restrict__ k_s, u16* __restrict__ v_s) {
  const int s = blockIdx.x;
  const int d = threadIdx.x;
  __shared__ float row[NPROJ];
  __shared__ float red[12][4];
  const float* yr = Y + (size_t)s * NPROJP;
  for (int u = d; u < NPROJ; u += 256) row[u] = yr[u];
  __syncthreads();
  const int i = d >> 1;
  const float cf = cosT[s * 128 + i];
  const float sf = sinT[s * 128 + i];
  const bool odd = d & 1;
  float bq[6], bk[2], bv[2];
#pragma unroll
  for (int r = 0; r < 6; ++r) {
    float x1 = row[64 + r*256 + 2*i], x2 = row[64 + r*256 + 2*i + 1];
    bq[r] = odd ? (x1*sf + x2*cf) : (x1*cf - x2*sf);
  }
#pragma unroll
  for (int r = 0; r < 2; ++r) {
    float x1 = row[1600 + r*256 + 2*i], x2 = row[1600 + r*256 + 2*i + 1];
    bk[r] = odd ? (x1*sf + x2*cf) : (x1*cf - x2*sf);
    bv[r] = row[2112 + r*256 + d];
  }
  float qv[8], kv[4], vv[4];
#pragma unroll
  for (int h = 0; h < 8; ++h) {
    float a = 0.f;
#pragma unroll
    for (int r = 0; r < 6; ++r) a += row[h*6 + r] * bq[r];
    qv[h] = a * (1.0f / 6.0f);
  }
#pragma unroll
  for (int c = 0; c < 4; ++c) {
    kv[c] = (row[48 + c*2]*bk[0] + row[48 + c*2 + 1]*bk[1]) * 0.5f;
    vv[c] = (row[56 + c*2]*bv[0] + row[56 + c*2 + 1]*bv[1]) * 0.5f;
  }
  const int lane = d & 63, wv = d >> 6;
#pragma unroll
  for (int t = 0; t < 12; ++t) {
    float x = (t < 8) ? qv[t] : kv[t - 8];
    float ss = x * x;
#pragma unroll
    for (int off = 32; off > 0; off >>= 1) ss += __shfl_xor(ss, off);
    if (lane == 0) red[t][wv] = ss;
  }
  __syncthreads();
  const float qwf = 1.0f + qw[d], kwf = 1.0f + kw[d];
#pragma unroll
  for (int h = 0; h < 8; ++h) {
    float v = red[h][0] + red[h][1] + red[h][2] + red[h][3];
    float r = rsqrtf(v * (1.0f/256.0f) + 1e-6f);
    q_s[((size_t)s*8 + h)*256 + d] = f2bf(qv[h] * r * qwf * 0.0625f);  // fold SCALING
  }
#pragma unroll
  for (int c = 0; c < 4; ++c) {
    float v = red[8+c][0] + red[8+c][1] + red[8+c][2] + red[8+c][3];
    float r = rsqrtf(v * (1.0f/256.0f) + 1e-6f);
    k_s[((size_t)s*4 + c)*256 + d] = f2bf(kv[c] * r * kwf);
    v_s[((size_t)s*4 + c)*256 + d] = f2bf(vv[c]);
  }
}

// ---------------- v (s,c,d) -> vT (c,d,s) 64x64 tile transpose ----------------
__global__ __launch_bounds__(256)
void k_vt(const u16* __restrict__ v_s, u16* __restrict__ vT) {
  __shared__ u16 tile[64][72];
  const int s0 = blockIdx.x * 64, d0 = blockIdx.y * 64, c = blockIdx.z;
  const int tid = threadIdx.x;
#pragma unroll
  for (int it = 0; it < 2; ++it) {
    const int u = it * 256 + tid;
    const int r = u >> 3, cc = u & 7;
    const u16* s = &v_s[(((size_t)(s0 + r))*4 + c)*256 + d0 + cc*8];
    ushort4 a = *(const ushort4*)s, b = *(const ushort4*)(s + 4);
    tile[r][cc*8+0]=a.x; tile[r][cc*8+1]=a.y; tile[r][cc*8+2]=a.z; tile[r][cc*8+3]=a.w;
    tile[r][cc*8+4]=b.x; tile[r][cc*8+5]=b.y; tile[r][cc*8+6]=b.z; tile[r][cc*8+7]=b.w;
  }
  __syncthreads();
#pragma unroll
  for (int it = 0; it < 2; ++it) {
    const int u = it * 256 + tid;
    const int dr = u >> 3, sc = u & 7;
    ushort4 a, b;
    a.x = tile[sc*8+0][dr]; a.y = tile[sc*8+1][dr]; a.z = tile[sc*8+2][dr]; a.w = tile[sc*8+3][dr];
    b.x = tile[sc*8+4][dr]; b.y = tile[sc*8+5][dr]; b.z = tile[sc*8+6][dr]; b.w = tile[sc*8+7][dr];
    u16* o = vT + ((size_t)c*256 + d0 + dr)*SEQ + s0 + sc*8;
    *(ushort4*)o = a; *(ushort4*)(o + 4) = b;
  }
}

// ---------------- flash attention, sliding window, softcap ----------------
// block = (64 queries, 1 head), 4 waves x 16 queries. Swapped QK^T: D[key][q],
// per-lane softmax state for query = lane&15. K LDS [64][256] + V^T LDS [256][64],
// both XOR-swizzled per 16B chunk (pre-swizzled global src, linear gl_lds dest).
// P (bf16) lives in dead Kt space per wave. Static LDS = exactly 64 KiB.
__global__ __launch_bounds__(256)
void k_attn(const u16* __restrict__ q_s, const u16* __restrict__ k_s,
            const u16* __restrict__ vT, const int* __restrict__ idx,
            u16* __restrict__ ao) {
  __shared__ u16 Kt[64 * 256];
  __shared__ u16 Vt[256 * 64];
  const int qt = blockIdx.x, h = blockIdx.y;
  const int c = h >> 1;
  const int q0 = qt * 64;
  const int tid = threadIdx.x;
  const int wid = tid >> 6, lane = tid & 63;
  const int l15 = lane & 15, g = lane >> 4;
  const int qrow = q0 + wid * 16 + l15;
  const int qpos = idx[qrow];
  u16* Pw = &Kt[wid * 1024];               // wave-private 16x64 bf16

  bf16x8 qf[8];
  const u16* qb = q_s + ((size_t)qrow * 8 + h) * 256;
#pragma unroll
  for (int kk = 0; kk < 8; ++kk) qf[kk] = *(const bf16x8*)(qb + kk*32 + g*8);

  f32x4 accO[16];
#pragma unroll
  for (int n = 0; n < 16; ++n) accO[n] = (f32x4){0.f,0.f,0.f,0.f};
  float mrun = -50.0f, lrun = 0.0f;        // softcap bounds real scores >= -50
  int t0 = q0 - (WIN - 1); if (t0 < 0) t0 = 0;
  const int kt_lo = t0 >> 6, kt_hi = qt;

  for (int kt = kt_lo; kt <= kt_hi; ++kt) {
    const int k0 = kt * 64;
#pragma unroll
    for (int i = 0; i < 8; ++i) {
      const int u = i * 256 + tid;
      { // K tile: row=key (u>>5), 32 chunks/row, swizzle chunk ^= row&7
        const int krow = u >> 5, cc = u & 31;
        const int cl = cc ^ (krow & 7);
        gl_lds16(k_s + (((size_t)(k0 + krow))*4 + c)*256 + cl*8,
                 &Kt[(i*256 + wid*64) * 8]);
      }
      { // V^T tile: row=d (u>>3), 8 chunks/row, swizzle chunk ^= row&7
        const int dr = u >> 3, kcs = u & 7;
        const int kc = kcs ^ (dr & 7);
        gl_lds16(vT + ((size_t)c*256 + dr)*SEQ + k0 + kc*8,
                 &Vt[(i*256 + wid*64) * 8]);
      }
    }
    __syncthreads();

    // S^T = K @ Q^T : D[key within 16][query=l15]
    f32x4 sc[4];
#pragma unroll
    for (int nk = 0; nk < 4; ++nk) sc[nk] = (f32x4){0.f,0.f,0.f,0.f};
#pragma unroll
    for (int nk = 0; nk < 4; ++nk) {
      const int krow = nk*16 + l15;
      const int sw = krow & 7;
#pragma unroll
      for (int kk = 0; kk < 8; ++kk) {
        const int cc = (4*kk + g) ^ sw;
        bf16x8 kf = *(const bf16x8*)&Kt[krow*256 + cc*8];
        sc[nk] = __builtin_amdgcn_mfma_f32_16x16x32_bf16(kf, qf[kk], sc[nk], 0, 0, 0);
      }
    }

    // softcap + window mask + online softmax (per-lane q = l15)
    float p[16];
    float tmax = -1e38f;
#pragma unroll
    for (int nk = 0; nk < 4; ++nk)
#pragma unroll
      for (int j = 0; j < 4; ++j) {
        float x = sc[nk][j];
        float e = __expf(-0.04f * fabsf(x));            // 2/SOFTCAP
        float t = copysignf(50.0f * (1.0f - e) / (1.0f + e), x);
        const int key = k0 + nk*16 + g*4 + j;           // D row = (lane>>4)*4+reg
        const int diff = qpos - key;
        const bool ok = (diff >= 0) && (diff < WIN);
        p[nk*4+j] = ok ? t : -1e38f;
        tmax = fmaxf(tmax, p[nk*4+j]);
      }
    tmax = fmaxf(tmax, __shfl_xor(tmax, 16));
    tmax = fmaxf(tmax, __shfl_xor(tmax, 32));
    const float mnew = fmaxf(mrun, tmax);
    const float scale = __expf(mrun - mnew);
    float psum = 0.0f;
#pragma unroll
    for (int t = 0; t < 16; ++t) { p[t] = __expf(p[t] - mnew); psum += p[t]; }
    psum += __shfl_xor(psum, 16);
    psum += __shfl_xor(psum, 32);
    lrun = lrun * scale + psum;
    mrun = mnew;
    float scj[4];
#pragma unroll
    for (int j = 0; j < 4; ++j) scj[j] = __shfl(scale, g*4 + j); // scale of O-row
#pragma unroll
    for (int n = 0; n < 16; ++n) {
      accO[n][0] *= scj[0]; accO[n][1] *= scj[1];
      accO[n][2] *= scj[2]; accO[n][3] *= scj[3];
    }

    __syncthreads();   // all QK reads of Kt done -> safe to write P into Kt space
#pragma unroll
    for (int nk = 0; nk < 4; ++nk) {
      const int ck = (nk*4 + g) ^ ((l15 & 7) << 1);     // 4-key chunk swizzle (even)
      ushort4 w;
      w.x = f2bf(p[nk*4+0]); w.y = f2bf(p[nk*4+1]);
      w.z = f2bf(p[nk*4+2]); w.w = f2bf(p[nk*4+3]);
      *(ushort4*)&Pw[l15*64 + ck*4] = w;
    }
    // O += P @ V
#pragma unroll
    for (int half = 0; half < 2; ++half) {
      const int cp = (half*8 + g*2) ^ ((l15 & 7) << 1);
      bf16x8 pa = *(const bf16x8*)&Pw[l15*64 + cp*4];
#pragma unroll
      for (int n = 0; n < 16; ++n) {
        const int vrow = n*16 + l15;
        const int kc = (half*4 + g) ^ (vrow & 7);
        bf16x8 vf = *(const bf16x8*)&Vt[vrow*64 + kc*8];
        accO[n] = __builtin_amdgcn_mfma_f32_16x16x32_bf16(pa, vf, accO[n], 0, 0, 0);
      }
    }
    __syncthreads();   // PV reads done before next tile's staging
  }

  const float linv = 1.0f / lrun;
  float lj[4];
#pragma unroll
  for (int j = 0; j < 4; ++j) lj[j] = __shfl(linv, g*4 + j);
#pragma unroll
  for (int n = 0; n < 16; ++n)
#pragma unroll
    for (int j = 0; j < 4; ++j) {
      const int r = q0 + wid*16 + g*4 + j;
      ao[(size_t)r * HIDN + h*256 + n*16 + l15] = f2bf(accO[n][j] * lj[j]);
    }
}

// ---------------- launch ----------------
extern "C" void kernel_launch(void* const* d_in, const int* in_sizes, int n_in,
                              void* d_out, int out_size, void* d_ws, size_t ws_size,
                              hipStream_t stream) {
  const float* x    = (const float*)d_in[0];
  const float* fcos = (const float*)d_in[1];
  const float* fsin = (const float*)d_in[2];
  const float* waq  = (const float*)d_in[3];
  const float* wak  = (const float*)d_in[4];
  const float* wav  = (const float*)d_in[5];
  const float* wbq  = (const float*)d_in[6];
  const float* wbk  = (const float*)d_in[7];
  const float* wbv  = (const float*)d_in[8];
  const float* wo   = (const float*)d_in[9];
  const float* qnw  = (const float*)d_in[10];
  const float* knw  = (const float*)d_in[11];
  const int*   idx  = (const int*)d_in[16];
  float* out = (float*)d_out;

  char* p = (char*)d_ws;
  u16*  xb   = (u16*)p;                 p += (size_t)SEQ*HIDN*2;        // x bf16
  u16*  wcat = (u16*)p;                 p += (size_t)NPROJP*HIDN*2;     // proj W bf16
  u16*  wob  = (u16*)p;                 p += (size_t)HIDN*HIDN*2;       // W_o bf16
  float* ypr = (float*)p;               p += (size_t)SEQ*NPROJP*4;      // proj out f32
  u16*  q_s  = (u16*)p;                 p += (size_t)SEQ*NHEAD*DH*2;    // q bf16 (scaled)
  u16*  k_s  = (u16*)p;                 p += (size_t)SEQ*NKVH*DH*2;     // k bf16
  u16*  v_s  = (u16*)p;                 p += (size_t)SEQ*NKVH*DH*2;     // v bf16
  u16*  vT   = (u16*)p;                 p += (size_t)SEQ*NKVH*DH*2;     // v^T bf16
  u16*  ao   = (u16*)p;                 p += (size_t)SEQ*HIDN*2;        // attn out bf16
  // total ~139 MB of d_ws

  k_cvt <<<(SEQ*HIDN/4 + 255)/256, 256, 0, stream>>>(x, xb, SEQ*HIDN/4);
  k_cvt <<<(HIDN*HIDN/4 + 255)/256, 256, 0, stream>>>(wo, wob, HIDN*HIDN/4);
  k_wcat<<<NPROJP, 256, 0, stream>>>(waq, wak, wav, wbq, wbk, wbv, wcat);
  k_gemm_bt<<<dim3(NPROJP/128, SEQ/128), 256, 0, stream>>>(xb, wcat, ypr, SEQ, NPROJP, HIDN);
  k_qkv <<<SEQ, 256, 0, stream>>>(ypr, fcos, fsin, qnw, knw, q_s, k_s, v_s);
  k_vt  <<<dim3(SEQ/64, DH/64, NKVH), 256, 0, stream>>>(v_s, vT);
  k_attn<<<dim3(SEQ/64, NHEAD), 256, 0, stream>>>(q_s, k_s, vT, idx, ao);
  k_gemm_bt<<<dim3(HIDN/128, SEQ/128), 256, 0, stream>>>(ao, wob, out, SEQ, HIDN, HIDN);
}

// Round 2
// 263.068 us; speedup vs baseline: 1.1554x; 1.1554x over previous
//
#include <hip/hip_runtime.h>
#include <hip/hip_bf16.h>
#include <cstdint>
#include <cstddef>

// ---- problem constants ----
constexpr int SEQ   = 4096;
constexpr int HIDN  = 2048;
constexpr int NHEAD = 8;
constexpr int NKVH  = 4;
constexpr int DH    = 256;
constexpr int NQR   = 6;
constexpr int NPROJ = 2624;      // 48 + 8 + 8 + 1536 + 512 + 512
constexpr int NPROJP= 2688;      // padded to /128
constexpr int WIN   = 1024;

typedef __attribute__((ext_vector_type(4))) float f32x4;
typedef __attribute__((ext_vector_type(8))) short bf16x8;
typedef unsigned short u16;

__device__ __forceinline__ u16 f2bf(float x) {
  union { float f; uint32_t u; } v; v.f = x;
  uint32_t r = v.u + 0x7fffu + ((v.u >> 16) & 1u);
  return (u16)(r >> 16);
}

// async global->LDS, 16B per lane, dest = wave-uniform base + lane*16 (linear)
__device__ __forceinline__ void gl_lds16(const u16* g, u16* l) {
  __builtin_amdgcn_global_load_lds(
      (const __attribute__((address_space(1))) uint32_t*)g,
      (__attribute__((address_space(3))) uint32_t*)l, 16, 0, 0);
}

// barrier that drains only VMEM (staged gl_lds) — leaves nothing else pinned
__device__ __forceinline__ void sync_vm() {
  asm volatile("s_waitcnt vmcnt(0)" ::: "memory");
  __builtin_amdgcn_s_barrier();
  __builtin_amdgcn_sched_barrier(0);
}
// barrier that drains only LDS ops — in-flight gl_lds prefetch stays in flight
__device__ __forceinline__ void sync_lgkm() {
  asm volatile("s_waitcnt lgkmcnt(0)" ::: "memory");
  __builtin_amdgcn_s_barrier();
  __builtin_amdgcn_sched_barrier(0);
}

// ---------------- f32 -> bf16 convert (vectorized x4) ----------------
__global__ __launch_bounds__(256) void k_cvt(const float* __restrict__ src,
                                             u16* __restrict__ dst, int n4) {
  int i = blockIdx.x * 256 + threadIdx.x;
  if (i >= n4) return;
  float4 v = ((const float4*)src)[i];
  ushort4 o; o.x = f2bf(v.x); o.y = f2bf(v.y); o.z = f2bf(v.z); o.w = f2bf(v.w);
  ((ushort4*)dst)[i] = o;
}

// ---------------- build concatenated projection weight (bf16, padded) ----------------
__global__ __launch_bounds__(256) void k_wcat(
    const float* __restrict__ waq, const float* __restrict__ wak,
    const float* __restrict__ wav, const float* __restrict__ wbq,
    const float* __restrict__ wbk, const float* __restrict__ wbv,
    u16* __restrict__ wcat) {
  const int r = blockIdx.x;            // 0..2687
  const int col0 = threadIdx.x * 8;    // 8 cols per thread
  u16* out = wcat + (size_t)r * HIDN + col0;
  const float* src = nullptr; int rr = 0;
  if      (r < 48)   { src = waq; rr = r; }
  else if (r < 56)   { src = wak; rr = r - 48; }
  else if (r < 64)   { src = wav; rr = r - 56; }
  else if (r < 1600) { src = wbq; rr = r - 64; }
  else if (r < 2112) { src = wbk; rr = r - 1600; }
  else if (r < 2624) { src = wbv; rr = r - 2112; }
  if (!src) {
    ushort4 z = {0,0,0,0}; ((ushort4*)out)[0] = z; ((ushort4*)out)[1] = z; return;
  }
  const float* s = src + (size_t)rr * HIDN + col0;
#pragma unroll
  for (int i = 0; i < 2; ++i) {
    float4 v = ((const float4*)s)[i];
    ushort4 o; o.x = f2bf(v.x); o.y = f2bf(v.y); o.z = f2bf(v.z); o.w = f2bf(v.w);
    ((ushort4*)out)[i] = o;
  }
}

// ---------------- bf16 GEMM: C(MxN) = A(MxK) @ B(NxK)^T, f32 out ----------------
__global__ __launch_bounds__(256)
void k_gemm_bt(const u16* __restrict__ A, const u16* __restrict__ Bm,
               float* __restrict__ C, int M, int N, int K) {
  __shared__ u16 lA[2][128 * 32];
  __shared__ u16 lB[2][128 * 32];
  const int tid = threadIdx.x;
  const int wid = tid >> 6, lane = tid & 63;
  const int l15 = lane & 15, g = lane >> 4;
  const int m0 = blockIdx.y * 128, n0 = blockIdx.x * 128;
  const int wr = wid >> 1, wc = wid & 1;
  f32x4 acc[4][4];
#pragma unroll
  for (int m = 0; m < 4; ++m)
#pragma unroll
    for (int n = 0; n < 4; ++n) acc[m][n] = (f32x4){0.f,0.f,0.f,0.f};
  const int NT = K >> 5;

  auto stage = [&](int buf, int kt) {
    const int k0 = kt << 5;
#pragma unroll
    for (int i = 0; i < 2; ++i) {
      const int u = i * 256 + tid;          // 16B chunk id: row = u>>2, slot = u&3
      const int row = u >> 2, cs = u & 3;
      const int cc = cs ^ ((row >> 1) & 3); // logical chunk held in this slot
      gl_lds16(A  + (size_t)(m0 + row) * K + k0 + cc * 8, &lA[buf][(i*256 + wid*64) * 8]);
      gl_lds16(Bm + (size_t)(n0 + row) * K + k0 + cc * 8, &lB[buf][(i*256 + wid*64) * 8]);
    }
  };

  stage(0, 0);
  int cur = 0;
  for (int kt = 0; kt < NT; ++kt) {
    __syncthreads();                         // staged buf[cur] ready (vmcnt drain)
    if (kt + 1 < NT) stage(cur ^ 1, kt + 1);
    bf16x8 af[4], bfr[4];
#pragma unroll
    for (int m = 0; m < 4; ++m) {
      const int row = wr*64 + m*16 + l15;
      const int cc = g ^ ((row >> 1) & 3);
      af[m] = *(const bf16x8*)&lA[cur][row*32 + cc*8];
    }
#pragma unroll
    for (int n = 0; n < 4; ++n) {
      const int row = wc*64 + n*16 + l15;
      const int cc = g ^ ((row >> 1) & 3);
      bfr[n] = *(const bf16x8*)&lB[cur][row*32 + cc*8];
    }
#pragma unroll
    for (int m = 0; m < 4; ++m)
#pragma unroll
      for (int n = 0; n < 4; ++n)
        acc[m][n] = __builtin_amdgcn_mfma_f32_16x16x32_bf16(af[m], bfr[n], acc[m][n], 0, 0, 0);
    cur ^= 1;
  }
#pragma unroll
  for (int m = 0; m < 4; ++m)
#pragma unroll
    for (int n = 0; n < 4; ++n)
#pragma unroll
      for (int j = 0; j < 4; ++j) {
        const int row = m0 + wr*64 + m*16 + g*4 + j;   // C/D: row=(lane>>4)*4+reg
        const int col = n0 + wc*64 + n*16 + l15;       //      col=lane&15
        C[(size_t)row * N + col] = acc[m][n][j];
      }
}

// ---------------- RoPE + rank-contract + RMSNorm -> q,k,v (bf16) ----------------
__global__ __launch_bounds__(256)
void k_qkv(const float* __restrict__ Y, const float* __restrict__ cosT,
           const float* __restrict__ sinT, const float* __restrict__ qw,
           const float* __restrict__ kw, u16* __restrict__ q_s,
           u16* __restrict__ k_s, u16* __restrict__ v_s) {
  const int s = blockIdx.x;
  const int d = threadIdx.x;
  __shared__ float row[NPROJ];
  __shared__ float red[12][4];
  const float* yr = Y + (size_t)s * NPROJP;
  for (int u = d; u < NPROJ; u += 256) row[u] = yr[u];
  __syncthreads();
  const int i = d >> 1;
  const float cf = cosT[s * 128 + i];
  const float sf = sinT[s * 128 + i];
  const bool odd = d & 1;
  float bq[6], bk[2], bv[2];
#pragma unroll
  for (int r = 0; r < 6; ++r) {
    float x1 = row[64 + r*256 + 2*i], x2 = row[64 + r*256 + 2*i + 1];
    bq[r] = odd ? (x1*sf + x2*cf) : (x1*cf - x2*sf);
  }
#pragma unroll
  for (int r = 0; r < 2; ++r) {
    float x1 = row[1600 + r*256 + 2*i], x2 = row[1600 + r*256 + 2*i + 1];
    bk[r] = odd ? (x1*sf + x2*cf) : (x1*cf - x2*sf);
    bv[r] = row[2112 + r*256 + d];
  }
  float qv[8], kv[4], vv[4];
#pragma unroll
  for (int h = 0; h < 8; ++h) {
    float a = 0.f;
#pragma unroll
    for (int r = 0; r < 6; ++r) a += row[h*6 + r] * bq[r];
    qv[h] = a * (1.0f / 6.0f);
  }
#pragma unroll
  for (int c = 0; c < 4; ++c) {
    kv[c] = (row[48 + c*2]*bk[0] + row[48 + c*2 + 1]*bk[1]) * 0.5f;
    vv[c] = (row[56 + c*2]*bv[0] + row[56 + c*2 + 1]*bv[1]) * 0.5f;
  }
  const int lane = d & 63, wv = d >> 6;
#pragma unroll
  for (int t = 0; t < 12; ++t) {
    float x = (t < 8) ? qv[t] : kv[t - 8];
    float ss = x * x;
#pragma unroll
    for (int off = 32; off > 0; off >>= 1) ss += __shfl_xor(ss, off);
    if (lane == 0) red[t][wv] = ss;
  }
  __syncthreads();
  const float qwf = 1.0f + qw[d], kwf = 1.0f + kw[d];
#pragma unroll
  for (int h = 0; h < 8; ++h) {
    float v = red[h][0] + red[h][1] + red[h][2] + red[h][3];
    float r = rsqrtf(v * (1.0f/256.0f) + 1e-6f);
    q_s[((size_t)s*8 + h)*256 + d] = f2bf(qv[h] * r * qwf * 0.0625f);  // fold SCALING
  }
#pragma unroll
  for (int c = 0; c < 4; ++c) {
    float v = red[8+c][0] + red[8+c][1] + red[8+c][2] + red[8+c][3];
    float r = rsqrtf(v * (1.0f/256.0f) + 1e-6f);
    k_s[((size_t)s*4 + c)*256 + d] = f2bf(kv[c] * r * kwf);
    v_s[((size_t)s*4 + c)*256 + d] = f2bf(vv[c]);
  }
}

// ---------------- v (s,c,d) -> vT (c,d,s) 64x64 tile transpose ----------------
__global__ __launch_bounds__(256)
void k_vt(const u16* __restrict__ v_s, u16* __restrict__ vT) {
  __shared__ u16 tile[64][72];
  const int s0 = blockIdx.x * 64, d0 = blockIdx.y * 64, c = blockIdx.z;
  const int tid = threadIdx.x;
#pragma unroll
  for (int it = 0; it < 2; ++it) {
    const int u = it * 256 + tid;
    const int r = u >> 3, cc = u & 7;
    const u16* s = &v_s[(((size_t)(s0 + r))*4 + c)*256 + d0 + cc*8];
    ushort4 a = *(const ushort4*)s, b = *(const ushort4*)(s + 4);
    tile[r][cc*8+0]=a.x; tile[r][cc*8+1]=a.y; tile[r][cc*8+2]=a.z; tile[r][cc*8+3]=a.w;
    tile[r][cc*8+4]=b.x; tile[r][cc*8+5]=b.y; tile[r][cc*8+6]=b.z; tile[r][cc*8+7]=b.w;
  }
  __syncthreads();
#pragma unroll
  for (int it = 0; it < 2; ++it) {
    const int u = it * 256 + tid;
    const int dr = u >> 3, sc = u & 7;
    ushort4 a, b;
    a.x = tile[sc*8+0][dr]; a.y = tile[sc*8+1][dr]; a.z = tile[sc*8+2][dr]; a.w = tile[sc*8+3][dr];
    b.x = tile[sc*8+4][dr]; b.y = tile[sc*8+5][dr]; b.z = tile[sc*8+6][dr]; b.w = tile[sc*8+7][dr];
    u16* o = vT + ((size_t)c*256 + d0 + dr)*SEQ + s0 + sc*8;
    *(ushort4*)o = a; *(ushort4*)(o + 4) = b;
  }
}

// ---------------- flash attention, sliding window, softcap ----------------
// KVBLK=32, double-buffered K/V staging with split barriers:
//   top: vmcnt(0)+s_barrier  (drains stage issued a full tile ago -> ~free)
//   mid: lgkmcnt(0)+s_barrier (orders QK reads vs P write; prefetch stays live)
// Swapped QK^T (D[key][q], q = lane&15), P in dead Kt space (stride 40),
// defer-max rescale (THR=8), per-head XCD affinity (h = blockIdx.x & 7).
__global__ __launch_bounds__(256)
void k_attn(const u16* __restrict__ q_s, const u16* __restrict__ k_s,
            const u16* __restrict__ vT, const int* __restrict__ idx,
            u16* __restrict__ ao) {
  __shared__ u16 Kt[2][32 * 256];   // 16 KB per buffer
  __shared__ u16 Vt[2][256 * 32];   // 16 KB per buffer  (total 64 KB)
  const int b = blockIdx.x;
  const int h = b & 7, qt = b >> 3;         // head -> XCD affinity
  const int c = h >> 1;
  const int q0 = qt * 64;
  const int tid = threadIdx.x;
  const int wid = tid >> 6, lane = tid & 63;
  const int l15 = lane & 15, g = lane >> 4;
  const int qrow = q0 + wid * 16 + l15;
  const int qpos = idx[qrow];

  bf16x8 qf[8];
  const u16* qb = q_s + ((size_t)qrow * 8 + h) * 256;
#pragma unroll
  for (int kk = 0; kk < 8; ++kk) qf[kk] = *(const bf16x8*)(qb + kk*32 + g*8);

  f32x4 accO[16];
#pragma unroll
  for (int n = 0; n < 16; ++n) accO[n] = (f32x4){0.f,0.f,0.f,0.f};
  float mrun = -50.0f, lrun = 0.0f;         // softcap bounds real scores >= -50
  int t0 = q0 - (WIN - 1); if (t0 < 0) t0 = 0;
  const int kt_lo = t0 >> 5, kt_hi = 2*qt + 1;

  auto stage = [&](int buf, int kt) {
    const int k0 = kt << 5;
#pragma unroll
    for (int i = 0; i < 4; ++i) {
      const int u = i * 256 + tid;
      { // K tile [32][256]: row = u>>5, 32 chunks/row, swizzle chunk ^= row&7
        const int row = u >> 5, cc = u & 31;
        const int cl = cc ^ (row & 7);
        gl_lds16(k_s + (((size_t)(k0 + row))*4 + c)*256 + cl*8,
                 &Kt[buf][(i*256 + wid*64) * 8]);
      }
      { // V^T tile [256][32]: row = u>>2 (d), 4 chunks/row, swizzle ^= (dr>>1)&3
        const int dr = u >> 2, pc = u & 3;
        const int lc = pc ^ ((dr >> 1) & 3);
        gl_lds16(vT + ((size_t)c*256 + dr)*SEQ + k0 + lc*8,
                 &Vt[buf][(i*256 + wid*64) * 8]);
      }
    }
  };

  stage(0, kt_lo);
  int cur = 0;
  for (int kt = kt_lo; kt <= kt_hi; ++kt) {
    const int k0 = kt * 32;
    sync_vm();                                // buf[cur] staged (issued 1 tile ago)
    if (kt < kt_hi) stage(cur ^ 1, kt + 1);   // prefetch stays in flight past mid

    // S^T = K @ Q^T : D[key within 16][query=l15]
    f32x4 sc2[2];
#pragma unroll
    for (int nk = 0; nk < 2; ++nk) sc2[nk] = (f32x4){0.f,0.f,0.f,0.f};
#pragma unroll
    for (int nk = 0; nk < 2; ++nk) {
      const int krow = nk*16 + l15;
      const int sw = krow & 7;
#pragma unroll
      for (int kk = 0; kk < 8; ++kk) {
        const int cc = (4*kk + g) ^ sw;
        bf16x8 kf = *(const bf16x8*)&Kt[cur][krow*256 + cc*8];
        sc2[nk] = __builtin_amdgcn_mfma_f32_16x16x32_bf16(kf, qf[kk], sc2[nk], 0, 0, 0);
      }
    }

    // softcap + window mask + online softmax (per-lane q = l15)
    float p[8];
    float tmax = -1e38f;
#pragma unroll
    for (int nk = 0; nk < 2; ++nk)
#pragma unroll
      for (int j = 0; j < 4; ++j) {
        float x = sc2[nk][j];
        float e = __expf(-0.04f * fabsf(x));            // 2/SOFTCAP
        float t = copysignf(50.0f * (1.0f - e) / (1.0f + e), x);
        const int key = k0 + nk*16 + g*4 + j;           // D row = (lane>>4)*4+reg
        const int diff = qpos - key;
        const bool ok = (diff >= 0) && (diff < WIN);
        p[nk*4+j] = ok ? t : -1e38f;
        tmax = fmaxf(tmax, p[nk*4+j]);
      }
    tmax = fmaxf(tmax, __shfl_xor(tmax, 16));
    tmax = fmaxf(tmax, __shfl_xor(tmax, 32));
    // defer-max (T13): only rescale when the running max grew by > 8
    if (__any(tmax > mrun + 8.0f)) {
      const float mnew = fmaxf(mrun, tmax);
      const float scale = __expf(mrun - mnew);
      float scj[4];
#pragma unroll
      for (int j = 0; j < 4; ++j) scj[j] = __shfl(scale, g*4 + j);
#pragma unroll
      for (int n = 0; n < 16; ++n) {
        accO[n][0] *= scj[0]; accO[n][1] *= scj[1];
        accO[n][2] *= scj[2]; accO[n][3] *= scj[3];
      }
      lrun *= scale;
      mrun = mnew;
    }
    float psum = 0.0f;
#pragma unroll
    for (int t = 0; t < 8; ++t) { p[t] = __expf(p[t] - mrun); psum += p[t]; }
    psum += __shfl_xor(psum, 16);
    psum += __shfl_xor(psum, 32);
    lrun += psum;

    sync_lgkm();   // all QK reads of Kt[cur] done; gl_lds prefetch NOT drained
    u16* Pw = &Kt[cur][wid * 2048];           // wave-private P [16][40] (padded)
#pragma unroll
    for (int nk = 0; nk < 2; ++nk) {
      ushort4 w;
      w.x = f2bf(p[nk*4+0]); w.y = f2bf(p[nk*4+1]);
      w.z = f2bf(p[nk*4+2]); w.w = f2bf(p[nk*4+3]);
      *(ushort4*)&Pw[l15*40 + nk*16 + g*4] = w;
    }
    // O += P @ V   (A-frag: P[q=l15][k=g*8..], B-frag: V^T[d=n*16+l15][k])
    bf16x8 pa = *(const bf16x8*)&Pw[l15*40 + g*8];
#pragma unroll
    for (int n = 0; n < 16; ++n) {
      const int dr = n*16 + l15;
      const int pc = g ^ ((dr >> 1) & 3);
      bf16x8 vf = *(const bf16x8*)&Vt[cur][dr*32 + pc*8];
      accO[n] = __builtin_amdgcn_mfma_f32_16x16x32_bf16(pa, vf, accO[n], 0, 0, 0);
    }
    cur ^= 1;
  }

  const float linv = 1.0f / lrun;
  float lj[4];
#pragma unroll
  for (int j = 0; j < 4; ++j) lj[j] = __shfl(linv, g*4 + j);
#pragma unroll
  for (int n = 0; n < 16; ++n)
#pragma unroll
    for (int j = 0; j < 4; ++j) {
      const int r = q0 + wid*16 + g*4 + j;
      ao[(size_t)r * HIDN + h*256 + n*16 + l15] = f2bf(accO[n][j] * lj[j]);
    }
}

// ---------------- launch ----------------
extern "C" void kernel_launch(void* const* d_in, const int* in_sizes, int n_in,
                              void* d_out, int out_size, void* d_ws, size_t ws_size,
                              hipStream_t stream) {
  const float* x    = (const float*)d_in[0];
  const float* fcos = (const float*)d_in[1];
  const float* fsin = (const float*)d_in[2];
  const float* waq  = (const float*)d_in[3];
  const float* wak  = (const float*)d_in[4];
  const float* wav  = (const float*)d_in[5];
  const float* wbq  = (const float*)d_in[6];
  const float* wbk  = (const float*)d_in[7];
  const float* wbv  = (const float*)d_in[8];
  const float* wo   = (const float*)d_in[9];
  const float* qnw  = (const float*)d_in[10];
  const float* knw  = (const float*)d_in[11];
  const int*   idx  = (const int*)d_in[16];
  float* out = (float*)d_out;

  char* p = (char*)d_ws;
  u16*  xb   = (u16*)p;                 p += (size_t)SEQ*HIDN*2;        // x bf16
  u16*  wcat = (u16*)p;                 p += (size_t)NPROJP*HIDN*2;     // proj W bf16
  u16*  wob  = (u16*)p;                 p += (size_t)HIDN*HIDN*2;       // W_o bf16
  float* ypr = (float*)p;               p += (size_t)SEQ*NPROJP*4;      // proj out f32
  u16*  q_s  = (u16*)p;                 p += (size_t)SEQ*NHEAD*DH*2;    // q bf16 (scaled)
  u16*  k_s  = (u16*)p;                 p += (size_t)SEQ*NKVH*DH*2;     // k bf16
  u16*  v_s  = (u16*)p;                 p += (size_t)SEQ*NKVH*DH*2;     // v bf16
  u16*  vT   = (u16*)p;                 p += (size_t)SEQ*NKVH*DH*2;     // v^T bf16
  u16*  ao   = (u16*)p;                 p += (size_t)SEQ*HIDN*2;        // attn out bf16

  k_cvt <<<(SEQ*HIDN/4 + 255)/256, 256, 0, stream>>>(x, xb, SEQ*HIDN/4);
  k_cvt <<<(HIDN*HIDN/4 + 255)/256, 256, 0, stream>>>(wo, wob, HIDN*HIDN/4);
  k_wcat<<<NPROJP, 256, 0, stream>>>(waq, wak, wav, wbq, wbk, wbv, wcat);
  k_gemm_bt<<<dim3(NPROJP/128, SEQ/128), 256, 0, stream>>>(xb, wcat, ypr, SEQ, NPROJP, HIDN);
  k_qkv <<<SEQ, 256, 0, stream>>>(ypr, fcos, fsin, qnw, knw, q_s, k_s, v_s);
  k_vt  <<<dim3(SEQ/64, DH/64, NKVH), 256, 0, stream>>>(v_s, vT);
  k_attn<<<dim3(SEQ/64 * NHEAD), 256, 0, stream>>>(q_s, k_s, vT, idx, ao);
  k_gemm_bt<<<dim3(HIDN/128, SEQ/128), 256, 0, stream>>>(ao, wob, out, SEQ, HIDN, HIDN);
}

// Round 3
// 253.731 us; speedup vs baseline: 1.1979x; 1.0368x over previous
//
#include <hip/hip_runtime.h>
#include <hip/hip_bf16.h>
#include <cstdint>
#include <cstddef>

// ---- problem constants ----
constexpr int SEQ   = 4096;
constexpr int HIDN  = 2048;
constexpr int NHEAD = 8;
constexpr int NKVH  = 4;
constexpr int DH    = 256;
constexpr int NPROJ = 2624;      // 48 + 8 + 8 + 1536 + 512 + 512
constexpr int NPROJP= 2688;      // padded to /128
constexpr int WIN   = 1024;

typedef __attribute__((ext_vector_type(4))) float f32x4;
typedef __attribute__((ext_vector_type(8))) short bf16x8;
typedef unsigned short u16;

__device__ __forceinline__ u16 f2bf(float x) {
  union { float f; uint32_t u; } v; v.f = x;
  uint32_t r = v.u + 0x7fffu + ((v.u >> 16) & 1u);
  return (u16)(r >> 16);
}

__device__ __forceinline__ uint32_t cvtpk(float lo, float hi) {
  uint32_t r;
  asm("v_cvt_pk_bf16_f32 %0, %1, %2" : "=v"(r) : "v"(lo), "v"(hi));
  return r;
}

// async global->LDS, 16B per lane, dest = wave-uniform base + lane*16 (linear)
__device__ __forceinline__ void gl_lds16(const u16* g, u16* l) {
  __builtin_amdgcn_global_load_lds(
      (const __attribute__((address_space(1))) uint32_t*)g,
      (__attribute__((address_space(3))) uint32_t*)l, 16, 0, 0);
}

// barrier draining only VMEM (staged gl_lds); nothing else pinned
__device__ __forceinline__ void sync_vm() {
  asm volatile("s_waitcnt vmcnt(0)" ::: "memory");
  __builtin_amdgcn_s_barrier();
  __builtin_amdgcn_sched_barrier(0);
}

// ---------------- f32 -> bf16 convert (vectorized x4) ----------------
__global__ __launch_bounds__(256) void k_cvt(const float* __restrict__ src,
                                             u16* __restrict__ dst, int n4) {
  int i = blockIdx.x * 256 + threadIdx.x;
  if (i >= n4) return;
  float4 v = ((const float4*)src)[i];
  ushort4 o; o.x = f2bf(v.x); o.y = f2bf(v.y); o.z = f2bf(v.z); o.w = f2bf(v.w);
  ((ushort4*)dst)[i] = o;
}

// ---------------- build concatenated projection weight (bf16, padded) ----------------
__global__ __launch_bounds__(256) void k_wcat(
    const float* __restrict__ waq, const float* __restrict__ wak,
    const float* __restrict__ wav, const float* __restrict__ wbq,
    const float* __restrict__ wbk, const float* __restrict__ wbv,
    u16* __restrict__ wcat) {
  const int r = blockIdx.x;
  const int col0 = threadIdx.x * 8;
  u16* out = wcat + (size_t)r * HIDN + col0;
  const float* src = nullptr; int rr = 0;
  if      (r < 48)   { src = waq; rr = r; }
  else if (r < 56)   { src = wak; rr = r - 48; }
  else if (r < 64)   { src = wav; rr = r - 56; }
  else if (r < 1600) { src = wbq; rr = r - 64; }
  else if (r < 2112) { src = wbk; rr = r - 1600; }
  else if (r < 2624) { src = wbv; rr = r - 2112; }
  if (!src) {
    ushort4 z = {0,0,0,0}; ((ushort4*)out)[0] = z; ((ushort4*)out)[1] = z; return;
  }
  const float* s = src + (size_t)rr * HIDN + col0;
#pragma unroll
  for (int i = 0; i < 2; ++i) {
    float4 v = ((const float4*)s)[i];
    ushort4 o; o.x = f2bf(v.x); o.y = f2bf(v.y); o.z = f2bf(v.z); o.w = f2bf(v.w);
    ((ushort4*)out)[i] = o;
  }
}

// ---------------- bf16 GEMM: C(MxN) = A(MxK) @ B(NxK)^T, f32 out ----------------
__global__ __launch_bounds__(256)
void k_gemm_bt(const u16* __restrict__ A, const u16* __restrict__ Bm,
               float* __restrict__ C, int M, int N, int K) {
  __shared__ u16 lA[2][128 * 32];
  __shared__ u16 lB[2][128 * 32];
  const int tid = threadIdx.x;
  const int wid = tid >> 6, lane = tid & 63;
  const int l15 = lane & 15, g = lane >> 4;
  const int m0 = blockIdx.y * 128, n0 = blockIdx.x * 128;
  const int wr = wid >> 1, wc = wid & 1;
  f32x4 acc[4][4];
#pragma unroll
  for (int m = 0; m < 4; ++m)
#pragma unroll
    for (int n = 0; n < 4; ++n) acc[m][n] = (f32x4){0.f,0.f,0.f,0.f};
  const int NT = K >> 5;

  auto stage = [&](int buf, int kt) {
    const int k0 = kt << 5;
#pragma unroll
    for (int i = 0; i < 2; ++i) {
      const int u = i * 256 + tid;
      const int row = u >> 2, cs = u & 3;
      const int cc = cs ^ ((row >> 1) & 3);
      gl_lds16(A  + (size_t)(m0 + row) * K + k0 + cc * 8, &lA[buf][(i*256 + wid*64) * 8]);
      gl_lds16(Bm + (size_t)(n0 + row) * K + k0 + cc * 8, &lB[buf][(i*256 + wid*64) * 8]);
    }
  };

  stage(0, 0);
  int cur = 0;
  for (int kt = 0; kt < NT; ++kt) {
    __syncthreads();
    if (kt + 1 < NT) stage(cur ^ 1, kt + 1);
    bf16x8 af[4], bfr[4];
#pragma unroll
    for (int m = 0; m < 4; ++m) {
      const int row = wr*64 + m*16 + l15;
      const int cc = g ^ ((row >> 1) & 3);
      af[m] = *(const bf16x8*)&lA[cur][row*32 + cc*8];
    }
#pragma unroll
    for (int n = 0; n < 4; ++n) {
      const int row = wc*64 + n*16 + l15;
      const int cc = g ^ ((row >> 1) & 3);
      bfr[n] = *(const bf16x8*)&lB[cur][row*32 + cc*8];
    }
#pragma unroll
    for (int m = 0; m < 4; ++m)
#pragma unroll
      for (int n = 0; n < 4; ++n)
        acc[m][n] = __builtin_amdgcn_mfma_f32_16x16x32_bf16(af[m], bfr[n], acc[m][n], 0, 0, 0);
    cur ^= 1;
  }
#pragma unroll
  for (int m = 0; m < 4; ++m)
#pragma unroll
    for (int n = 0; n < 4; ++n)
#pragma unroll
      for (int j = 0; j < 4; ++j) {
        const int row = m0 + wr*64 + m*16 + g*4 + j;
        const int col = n0 + wc*64 + n*16 + l15;
        C[(size_t)row * N + col] = acc[m][n][j];
      }
}

// ---------------- RoPE + rank-contract + RMSNorm -> q,k,v (bf16) ----------------
__global__ __launch_bounds__(256)
void k_qkv(const float* __restrict__ Y, const float* __restrict__ cosT,
           const float* __restrict__ sinT, const float* __restrict__ qw,
           const float* __restrict__ kw, u16* __restrict__ q_s,
           u16* __restrict__ k_s, u16* __restrict__ v_s) {
  const int s = blockIdx.x;
  const int d = threadIdx.x;
  __shared__ float row[NPROJ];
  __shared__ float red[12][4];
  const float* yr = Y + (size_t)s * NPROJP;
  for (int u = d; u < NPROJ; u += 256) row[u] = yr[u];
  __syncthreads();
  const int i = d >> 1;
  const float cf = cosT[s * 128 + i];
  const float sf = sinT[s * 128 + i];
  const bool odd = d & 1;
  float bq[6], bk[2], bv[2];
#pragma unroll
  for (int r = 0; r < 6; ++r) {
    float x1 = row[64 + r*256 + 2*i], x2 = row[64 + r*256 + 2*i + 1];
    bq[r] = odd ? (x1*sf + x2*cf) : (x1*cf - x2*sf);
  }
#pragma unroll
  for (int r = 0; r < 2; ++r) {
    float x1 = row[1600 + r*256 + 2*i], x2 = row[1600 + r*256 + 2*i + 1];
    bk[r] = odd ? (x1*sf + x2*cf) : (x1*cf - x2*sf);
    bv[r] = row[2112 + r*256 + d];
  }
  float qv[8], kv[4], vv[4];
#pragma unroll
  for (int h = 0; h < 8; ++h) {
    float a = 0.f;
#pragma unroll
    for (int r = 0; r < 6; ++r) a += row[h*6 + r] * bq[r];
    qv[h] = a * (1.0f / 6.0f);
  }
#pragma unroll
  for (int c = 0; c < 4; ++c) {
    kv[c] = (row[48 + c*2]*bk[0] + row[48 + c*2 + 1]*bk[1]) * 0.5f;
    vv[c] = (row[56 + c*2]*bv[0] + row[56 + c*2 + 1]*bv[1]) * 0.5f;
  }
  const int lane = d & 63, wv = d >> 6;
#pragma unroll
  for (int t = 0; t < 12; ++t) {
    float x = (t < 8) ? qv[t] : kv[t - 8];
    float ss = x * x;
#pragma unroll
    for (int off = 32; off > 0; off >>= 1) ss += __shfl_xor(ss, off);
    if (lane == 0) red[t][wv] = ss;
  }
  __syncthreads();
  const float qwf = 1.0f + qw[d], kwf = 1.0f + kw[d];
#pragma unroll
  for (int h = 0; h < 8; ++h) {
    float v = red[h][0] + red[h][1] + red[h][2] + red[h][3];
    float r = rsqrtf(v * (1.0f/256.0f) + 1e-6f);
    q_s[((size_t)s*8 + h)*256 + d] = f2bf(qv[h] * r * qwf * 0.0625f);  // fold SCALING
  }
#pragma unroll
  for (int c = 0; c < 4; ++c) {
    float v = red[8+c][0] + red[8+c][1] + red[8+c][2] + red[8+c][3];
    float r = rsqrtf(v * (1.0f/256.0f) + 1e-6f);
    k_s[((size_t)s*4 + c)*256 + d] = f2bf(kv[c] * r * kwf);
    v_s[((size_t)s*4 + c)*256 + d] = f2bf(vv[c]);
  }
}

// ---------------- v (s,c,d) -> vT (c,d,s) 64x64 tile transpose ----------------
__global__ __launch_bounds__(256)
void k_vt(const u16* __restrict__ v_s, u16* __restrict__ vT) {
  __shared__ u16 tile[64][72];
  const int s0 = blockIdx.x * 64, d0 = blockIdx.y * 64, c = blockIdx.z;
  const int tid = threadIdx.x;
#pragma unroll
  for (int it = 0; it < 2; ++it) {
    const int u = it * 256 + tid;
    const int r = u >> 3, cc = u & 7;
    const u16* s = &v_s[(((size_t)(s0 + r))*4 + c)*256 + d0 + cc*8];
    ushort4 a = *(const ushort4*)s, b = *(const ushort4*)(s + 4);
    tile[r][cc*8+0]=a.x; tile[r][cc*8+1]=a.y; tile[r][cc*8+2]=a.z; tile[r][cc*8+3]=a.w;
    tile[r][cc*8+4]=b.x; tile[r][cc*8+5]=b.y; tile[r][cc*8+6]=b.z; tile[r][cc*8+7]=b.w;
  }
  __syncthreads();
#pragma unroll
  for (int it = 0; it < 2; ++it) {
    const int u = it * 256 + tid;
    const int dr = u >> 3, sc = u & 7;
    ushort4 a, b;
    a.x = tile[sc*8+0][dr]; a.y = tile[sc*8+1][dr]; a.z = tile[sc*8+2][dr]; a.w = tile[sc*8+3][dr];
    b.x = tile[sc*8+4][dr]; b.y = tile[sc*8+5][dr]; b.z = tile[sc*8+6][dr]; b.w = tile[sc*8+7][dr];
    u16* o = vT + ((size_t)c*256 + d0 + dr)*SEQ + s0 + sc*8;
    *(ushort4*)o = a; *(ushort4*)(o + 4) = b;
  }
}

// ---------------- flash attention, sliding window, softcap ----------------
// Block = 32 queries x 2 heads (GQA pair shares K/V), 4 waves x 16 queries.
// KVBLK=32, double-buffered K+V, ONE barrier per tile (vmcnt+s_barrier).
// P in wave-private Pb (no inter-wave hazard -> no second barrier).
// Swizzle folded into precomputed per-lane base addresses (bank-optimal).
__global__ __launch_bounds__(256)
void k_attn(const u16* __restrict__ q_s, const u16* __restrict__ k_s,
            const u16* __restrict__ vT, const int* __restrict__ idx,
            u16* __restrict__ ao) {
  __shared__ u16 Kt[2][32 * 256];   // 16 KB x2
  __shared__ u16 Vt[2][256 * 32];   // 16 KB x2
  __shared__ u16 Pb[4][16 * 40];    // 5 KB wave-private P
  const int b = blockIdx.x;
  const int c = b & 3, qt = b >> 2;           // c -> XCD affinity (2 XCDs per c)
  const int q0 = qt * 32;
  const int tid = threadIdx.x;
  const int wid = tid >> 6, lane = tid & 63;
  const int l15 = lane & 15, g = lane >> 4;
  const int h = 2*c + (wid >> 1);             // waves 0,1 -> head 2c; 2,3 -> 2c+1
  const int qsub = wid & 1;
  const int qrow = q0 + qsub*16 + l15;
  const int qpos = idx[qrow];

  // Q fragments (16 chunks of 32 dims; lane supplies dims kk*32 + g*8..+7)
  bf16x8 qf[8];
  const u16* qb = q_s + ((size_t)qrow * 8 + h) * 256;
#pragma unroll
  for (int kk = 0; kk < 8; ++kk) qf[kk] = *(const bf16x8*)(qb + kk*32 + g*8);

  // precomputed swizzled LDS read bases (u16 indices)
  int kbase[8];
#pragma unroll
  for (int kk = 0; kk < 8; ++kk)
    kbase[kk] = l15*256 + (((4*kk + g) ^ (l15 & 7)) * 8);
  const int vbase = l15*32 + ((g ^ ((l15 >> 1) & 3)) * 8);
  u16* KtF = &Kt[0][0];
  u16* VtF = &Vt[0][0];
  u16* Pw  = &Pb[wid][0];

  f32x4 accO[16];
#pragma unroll
  for (int n = 0; n < 16; ++n) accO[n] = (f32x4){0.f,0.f,0.f,0.f};
  float mrun = -50.0f, lrun = 0.0f;

  int t0 = q0 - (WIN - 1); if (t0 < 0) t0 = 0;
  const int kt_lo = t0 >> 5, kt_hi = qt;

  // staging pointers (per-thread, strength-reduced)
  const int srow = tid >> 5;                   // 0..7
  const int scl  = (tid & 31) ^ srow;          // K stored-chunk swizzle
  const int vdr  = tid >> 2;                   // 0..63
  const int vlc  = (tid & 3) ^ ((tid >> 3) & 3);
  const u16* kg = k_s + (size_t)(kt_lo*32 + srow) * 1024 + c*256 + scl*8;
  const u16* vg = vT  + (size_t)c*1048576 + (size_t)vdr*4096 + kt_lo*32 + vlc*8;

  auto stage = [&](int buf) {
#pragma unroll
    for (int i = 0; i < 4; ++i)
      gl_lds16(kg + i*8192,   &Kt[buf][(i*256 + wid*64) * 8]);
#pragma unroll
    for (int i = 0; i < 4; ++i)
      gl_lds16(vg + i*262144, &Vt[buf][(i*256 + wid*64) * 8]);
  };

  stage(0);
  int cur = 0;
  for (int kt = kt_lo; kt <= kt_hi; ++kt) {
    const int k0 = kt * 32;
    sync_vm();                                 // buf[cur] staged (issued 1 tile ago)
    if (kt < kt_hi) { kg += 32768; vg += 32; stage(cur ^ 1); }

    // S^T = K @ Q^T : D[key][q=l15]
    const int kco = cur * 8192;
    f32x4 s0 = (f32x4){0.f,0.f,0.f,0.f}, s1 = (f32x4){0.f,0.f,0.f,0.f};
#pragma unroll
    for (int kk = 0; kk < 8; ++kk) {
      bf16x8 kf0 = *(const bf16x8*)&KtF[kbase[kk] + kco];
      bf16x8 kf1 = *(const bf16x8*)&KtF[kbase[kk] + kco + 4096];
      s0 = __builtin_amdgcn_mfma_f32_16x16x32_bf16(kf0, qf[kk], s0, 0, 0, 0);
      s1 = __builtin_amdgcn_mfma_f32_16x16x32_bf16(kf1, qf[kk], s1, 0, 0, 0);
    }

    // softcap: t = 50 - 100/(1+exp2(x*log2e/25)); handles +-inf correctly
    float tv[8];
#pragma unroll
    for (int nk = 0; nk < 2; ++nk)
#pragma unroll
      for (int j = 0; j < 4; ++j) {
        float x = (nk == 0) ? s0[j] : s1[j];
        float u = exp2f(x * 0.05770780163555854f);
        tv[nk*4+j] = fmaf(-100.0f, __builtin_amdgcn_rcpf(1.0f + u), 50.0f);
      }
    const int dbase = qpos - k0;
    if (kt == kt_hi) {                        // causal edge: key<=qpos
#pragma unroll
      for (int nk = 0; nk < 2; ++nk)
#pragma unroll
        for (int j = 0; j < 4; ++j)
          if (nk*16 + g*4 + j > dbase) tv[nk*4+j] = -1e38f;
    } else if (k0 < q0 - 992) {               // window edge: qpos-key<=1023
#pragma unroll
      for (int nk = 0; nk < 2; ++nk)
#pragma unroll
        for (int j = 0; j < 4; ++j)
          if (dbase - (nk*16 + g*4 + j) > 1023) tv[nk*4+j] = -1e38f;
    }

    float tmax = tv[0];
#pragma unroll
    for (int t = 1; t < 8; ++t) tmax = fmaxf(tmax, tv[t]);
    tmax = fmaxf(tmax, __shfl_xor(tmax, 16));
    tmax = fmaxf(tmax, __shfl_xor(tmax, 32));
    if (__any(tmax > mrun + 8.0f)) {          // defer-max (T13)
      const float mnew = fmaxf(mrun, tmax);
      const float scale = exp2f((mrun - mnew) * 1.442695041f);
      float scj[4];
#pragma unroll
      for (int j = 0; j < 4; ++j) scj[j] = __shfl(scale, g*4 + j);
#pragma unroll
      for (int n = 0; n < 16; ++n) {
        accO[n][0] *= scj[0]; accO[n][1] *= scj[1];
        accO[n][2] *= scj[2]; accO[n][3] *= scj[3];
      }
      lrun *= scale;
      mrun = mnew;
    }
    const float mr2 = mrun * 1.442695041f;
    float p[8], psum = 0.0f;
#pragma unroll
    for (int t = 0; t < 8; ++t) {
      p[t] = exp2f(fmaf(tv[t], 1.442695041f, -mr2));
      psum += p[t];
    }
    psum += __shfl_xor(psum, 16);
    psum += __shfl_xor(psum, 32);
    lrun += psum;

    // P -> wave-private LDS (bf16), then PV
    uint32_t a0 = cvtpk(p[0], p[1]), a1 = cvtpk(p[2], p[3]);
    uint32_t b0 = cvtpk(p[4], p[5]), b1 = cvtpk(p[6], p[7]);
    { uint2 w = {a0, a1}; *(uint2*)&Pw[l15*40 + g*4]      = w; }
    { uint2 w = {b0, b1}; *(uint2*)&Pw[l15*40 + 16 + g*4] = w; }
    bf16x8 pa = *(const bf16x8*)&Pw[l15*40 + g*8];
    const int vco = cur * 8192;
#pragma unroll
    for (int n = 0; n < 16; ++n) {
      bf16x8 vf = *(const bf16x8*)&VtF[vbase + vco + n*512];
      accO[n] = __builtin_amdgcn_mfma_f32_16x16x32_bf16(pa, vf, accO[n], 0, 0, 0);
    }
    cur ^= 1;
  }

  const float linv = 1.0f / lrun;
  float lj[4];
#pragma unroll
  for (int j = 0; j < 4; ++j) lj[j] = __shfl(linv, g*4 + j);
#pragma unroll
  for (int n = 0; n < 16; ++n)
#pragma unroll
    for (int j = 0; j < 4; ++j) {
      const int r = q0 + qsub*16 + g*4 + j;
      ao[(size_t)r * HIDN + h*256 + n*16 + l15] = f2bf(accO[n][j] * lj[j]);
    }
}

// ---------------- launch ----------------
extern "C" void kernel_launch(void* const* d_in, const int* in_sizes, int n_in,
                              void* d_out, int out_size, void* d_ws, size_t ws_size,
                              hipStream_t stream) {
  const float* x    = (const float*)d_in[0];
  const float* fcos = (const float*)d_in[1];
  const float* fsin = (const float*)d_in[2];
  const float* waq  = (const float*)d_in[3];
  const float* wak  = (const float*)d_in[4];
  const float* wav  = (const float*)d_in[5];
  const float* wbq  = (const float*)d_in[6];
  const float* wbk  = (const float*)d_in[7];
  const float* wbv  = (const float*)d_in[8];
  const float* wo   = (const float*)d_in[9];
  const float* qnw  = (const float*)d_in[10];
  const float* knw  = (const float*)d_in[11];
  const int*   idx  = (const int*)d_in[16];
  float* out = (float*)d_out;

  char* p = (char*)d_ws;
  u16*  xb   = (u16*)p;                 p += (size_t)SEQ*HIDN*2;
  u16*  wcat = (u16*)p;                 p += (size_t)NPROJP*HIDN*2;
  u16*  wob  = (u16*)p;                 p += (size_t)HIDN*HIDN*2;
  float* ypr = (float*)p;               p += (size_t)SEQ*NPROJP*4;
  u16*  q_s  = (u16*)p;                 p += (size_t)SEQ*NHEAD*DH*2;
  u16*  k_s  = (u16*)p;                 p += (size_t)SEQ*NKVH*DH*2;
  u16*  v_s  = (u16*)p;                 p += (size_t)SEQ*NKVH*DH*2;
  u16*  vT   = (u16*)p;                 p += (size_t)SEQ*NKVH*DH*2;
  u16*  ao   = (u16*)p;                 p += (size_t)SEQ*HIDN*2;

  k_cvt <<<(SEQ*HIDN/4 + 255)/256, 256, 0, stream>>>(x, xb, SEQ*HIDN/4);
  k_cvt <<<(HIDN*HIDN/4 + 255)/256, 256, 0, stream>>>(wo, wob, HIDN*HIDN/4);
  k_wcat<<<NPROJP, 256, 0, stream>>>(waq, wak, wav, wbq, wbk, wbv, wcat);
  k_gemm_bt<<<dim3(NPROJP/128, SEQ/128), 256, 0, stream>>>(xb, wcat, ypr, SEQ, NPROJP, HIDN);
  k_qkv <<<SEQ, 256, 0, stream>>>(ypr, fcos, fsin, qnw, knw, q_s, k_s, v_s);
  k_vt  <<<dim3(SEQ/64, DH/64, NKVH), 256, 0, stream>>>(v_s, vT);
  k_attn<<<dim3(SEQ/32 * NKVH), 256, 0, stream>>>(q_s, k_s, vT, idx, ao);
  k_gemm_bt<<<dim3(HIDN/128, SEQ/128), 256, 0, stream>>>(ao, wob, out, SEQ, HIDN, HIDN);
}

// Round 4
// 224.726 us; speedup vs baseline: 1.3525x; 1.1291x over previous
//
#include <hip/hip_runtime.h>
#include <hip/hip_bf16.h>
#include <cstdint>
#include <cstddef>

// ---- problem constants ----
constexpr int SEQ   = 4096;
constexpr int HIDN  = 2048;
constexpr int NHEAD = 8;
constexpr int NKVH  = 4;
constexpr int DH    = 256;
constexpr int NPROJ = 2624;      // 48 + 8 + 8 + 1536 + 512 + 512
constexpr int NPROJP= 2688;      // padded to /128
constexpr int WIN   = 1024;

typedef __attribute__((ext_vector_type(4))) float f32x4;
typedef __attribute__((ext_vector_type(8))) short bf16x8;
typedef unsigned short u16;

__device__ __forceinline__ u16 f2bf(float x) {
  union { float f; uint32_t u; } v; v.f = x;
  uint32_t r = v.u + 0x7fffu + ((v.u >> 16) & 1u);
  return (u16)(r >> 16);
}
__device__ __forceinline__ float bf2f(u16 v) {
  union { uint32_t u; float f; } w; w.u = (uint32_t)v << 16; return w.f;
}

__device__ __forceinline__ uint32_t cvtpk(float lo, float hi) {
  uint32_t r;
  asm("v_cvt_pk_bf16_f32 %0, %1, %2" : "=v"(r) : "v"(lo), "v"(hi));
  return r;
}

// async global->LDS, 16B per lane, dest = wave-uniform base + lane*16 (linear)
__device__ __forceinline__ void gl_lds16(const u16* g, u16* l) {
  __builtin_amdgcn_global_load_lds(
      (const __attribute__((address_space(1))) uint32_t*)g,
      (__attribute__((address_space(3))) uint32_t*)l, 16, 0, 0);
}

// barrier draining only VMEM (staged gl_lds); nothing else pinned
__device__ __forceinline__ void sync_vm() {
  asm volatile("s_waitcnt vmcnt(0)" ::: "memory");
  __builtin_amdgcn_s_barrier();
  __builtin_amdgcn_sched_barrier(0);
}

// bijective XCD-aware workgroup remap (m204)
__device__ __forceinline__ int xcd_swz(int wg, int nwg) {
  const int q = nwg >> 3, r = nwg & 7;
  const int xcd = wg & 7, lo = wg >> 3;
  return (xcd < r ? xcd * (q + 1) : r * (q + 1) + (xcd - r) * q) + lo;
}

// ---------------- f32 -> bf16 convert (vectorized x4) ----------------
__global__ __launch_bounds__(256) void k_cvt(const float* __restrict__ src,
                                             u16* __restrict__ dst, int n4) {
  int i = blockIdx.x * 256 + threadIdx.x;
  if (i >= n4) return;
  float4 v = ((const float4*)src)[i];
  ushort4 o; o.x = f2bf(v.x); o.y = f2bf(v.y); o.z = f2bf(v.z); o.w = f2bf(v.w);
  ((ushort4*)dst)[i] = o;
}

// ---------------- build concatenated projection weight (bf16, padded) ----------------
__global__ __launch_bounds__(256) void k_wcat(
    const float* __restrict__ waq, const float* __restrict__ wak,
    const float* __restrict__ wav, const float* __restrict__ wbq,
    const float* __restrict__ wbk, const float* __restrict__ wbv,
    u16* __restrict__ wcat) {
  const int r = blockIdx.x;
  const int col0 = threadIdx.x * 8;
  u16* out = wcat + (size_t)r * HIDN + col0;
  const float* src = nullptr; int rr = 0;
  if      (r < 48)   { src = waq; rr = r; }
  else if (r < 56)   { src = wak; rr = r - 48; }
  else if (r < 64)   { src = wav; rr = r - 56; }
  else if (r < 1600) { src = wbq; rr = r - 64; }
  else if (r < 2112) { src = wbk; rr = r - 1600; }
  else if (r < 2624) { src = wbv; rr = r - 2112; }
  if (!src) {
    ushort4 z = {0,0,0,0}; ((ushort4*)out)[0] = z; ((ushort4*)out)[1] = z; return;
  }
  const float* s = src + (size_t)rr * HIDN + col0;
#pragma unroll
  for (int i = 0; i < 2; ++i) {
    float4 v = ((const float4*)s)[i];
    ushort4 o; o.x = f2bf(v.x); o.y = f2bf(v.y); o.z = f2bf(v.z); o.w = f2bf(v.w);
    ((ushort4*)out)[i] = o;
  }
}

// ---------------- bf16 GEMM: C(MxN) = A(MxK) @ B(NxK)^T ----------------
// OBF16=1 -> bf16 C output, else f32. XCD-aware block swizzle (T1).
template<int OBF16>
__global__ __launch_bounds__(256)
void k_gemm_bt(const u16* __restrict__ A, const u16* __restrict__ Bm,
               void* __restrict__ Cv, int M, int N, int K) {
  __shared__ u16 lA[2][128 * 32];
  __shared__ u16 lB[2][128 * 32];
  const int tid = threadIdx.x;
  const int wid = tid >> 6, lane = tid & 63;
  const int l15 = lane & 15, g = lane >> 4;
  const int nwg = gridDim.x * gridDim.y;
  int wg = xcd_swz(blockIdx.y * gridDim.x + blockIdx.x, nwg);
  const int m0 = (wg / gridDim.x) * 128, n0 = (wg % gridDim.x) * 128;
  const int wr = wid >> 1, wc = wid & 1;
  f32x4 acc[4][4];
#pragma unroll
  for (int m = 0; m < 4; ++m)
#pragma unroll
    for (int n = 0; n < 4; ++n) acc[m][n] = (f32x4){0.f,0.f,0.f,0.f};
  const int NT = K >> 5;

  auto stage = [&](int buf, int kt) {
    const int k0 = kt << 5;
#pragma unroll
    for (int i = 0; i < 2; ++i) {
      const int u = i * 256 + tid;
      const int row = u >> 2, cs = u & 3;
      const int cc = cs ^ ((row >> 1) & 3);
      gl_lds16(A  + (size_t)(m0 + row) * K + k0 + cc * 8, &lA[buf][(i*256 + wid*64) * 8]);
      gl_lds16(Bm + (size_t)(n0 + row) * K + k0 + cc * 8, &lB[buf][(i*256 + wid*64) * 8]);
    }
  };

  stage(0, 0);
  int cur = 0;
  for (int kt = 0; kt < NT; ++kt) {
    __syncthreads();
    if (kt + 1 < NT) stage(cur ^ 1, kt + 1);
    bf16x8 af[4], bfr[4];
#pragma unroll
    for (int m = 0; m < 4; ++m) {
      const int row = wr*64 + m*16 + l15;
      const int cc = g ^ ((row >> 1) & 3);
      af[m] = *(const bf16x8*)&lA[cur][row*32 + cc*8];
    }
#pragma unroll
    for (int n = 0; n < 4; ++n) {
      const int row = wc*64 + n*16 + l15;
      const int cc = g ^ ((row >> 1) & 3);
      bfr[n] = *(const bf16x8*)&lB[cur][row*32 + cc*8];
    }
    __builtin_amdgcn_s_setprio(1);
#pragma unroll
    for (int m = 0; m < 4; ++m)
#pragma unroll
      for (int n = 0; n < 4; ++n)
        acc[m][n] = __builtin_amdgcn_mfma_f32_16x16x32_bf16(af[m], bfr[n], acc[m][n], 0, 0, 0);
    __builtin_amdgcn_s_setprio(0);
    cur ^= 1;
  }
#pragma unroll
  for (int m = 0; m < 4; ++m)
#pragma unroll
    for (int n = 0; n < 4; ++n)
#pragma unroll
      for (int j = 0; j < 4; ++j) {
        const int row = m0 + wr*64 + m*16 + g*4 + j;
        const int col = n0 + wc*64 + n*16 + l15;
        if constexpr (OBF16) ((u16*)Cv)[(size_t)row * N + col] = f2bf(acc[m][n][j]);
        else                 ((float*)Cv)[(size_t)row * N + col] = acc[m][n][j];
      }
}

// ---------------- RoPE + rank-contract + RMSNorm -> q,k,v (bf16) ----------------
__global__ __launch_bounds__(256)
void k_qkv(const u16* __restrict__ Y, const float* __restrict__ cosT,
           const float* __restrict__ sinT, const float* __restrict__ qw,
           const float* __restrict__ kw, u16* __restrict__ q_s,
           u16* __restrict__ k_s, u16* __restrict__ v_s) {
  const int s = blockIdx.x;
  const int d = threadIdx.x;
  __shared__ float row[NPROJ];
  __shared__ float red[12][4];
  const u16* yr = Y + (size_t)s * NPROJP;
  for (int u4 = d; u4 < NPROJ/4; u4 += 256) {
    ushort4 v4 = ((const ushort4*)yr)[u4];
    row[u4*4+0] = bf2f(v4.x); row[u4*4+1] = bf2f(v4.y);
    row[u4*4+2] = bf2f(v4.z); row[u4*4+3] = bf2f(v4.w);
  }
  __syncthreads();
  const int i = d >> 1;
  const float cf = cosT[s * 128 + i];
  const float sf = sinT[s * 128 + i];
  const bool odd = d & 1;
  float bq[6], bk[2], bv[2];
#pragma unroll
  for (int r = 0; r < 6; ++r) {
    float x1 = row[64 + r*256 + 2*i], x2 = row[64 + r*256 + 2*i + 1];
    bq[r] = odd ? (x1*sf + x2*cf) : (x1*cf - x2*sf);
  }
#pragma unroll
  for (int r = 0; r < 2; ++r) {
    float x1 = row[1600 + r*256 + 2*i], x2 = row[1600 + r*256 + 2*i + 1];
    bk[r] = odd ? (x1*sf + x2*cf) : (x1*cf - x2*sf);
    bv[r] = row[2112 + r*256 + d];
  }
  float qv[8], kv[4], vv[4];
#pragma unroll
  for (int h = 0; h < 8; ++h) {
    float a = 0.f;
#pragma unroll
    for (int r = 0; r < 6; ++r) a += row[h*6 + r] * bq[r];
    qv[h] = a * (1.0f / 6.0f);
  }
#pragma unroll
  for (int c = 0; c < 4; ++c) {
    kv[c] = (row[48 + c*2]*bk[0] + row[48 + c*2 + 1]*bk[1]) * 0.5f;
    vv[c] = (row[56 + c*2]*bv[0] + row[56 + c*2 + 1]*bv[1]) * 0.5f;
  }
  const int lane = d & 63, wv = d >> 6;
#pragma unroll
  for (int t = 0; t < 12; ++t) {
    float x = (t < 8) ? qv[t] : kv[t - 8];
    float ss = x * x;
#pragma unroll
    for (int off = 32; off > 0; off >>= 1) ss += __shfl_xor(ss, off);
    if (lane == 0) red[t][wv] = ss;
  }
  __syncthreads();
  const float qwf = 1.0f + qw[d], kwf = 1.0f + kw[d];
#pragma unroll
  for (int h = 0; h < 8; ++h) {
    float v = red[h][0] + red[h][1] + red[h][2] + red[h][3];
    float r = rsqrtf(v * (1.0f/256.0f) + 1e-6f);
    q_s[((size_t)s*8 + h)*256 + d] = f2bf(qv[h] * r * qwf * 0.0625f);  // fold SCALING
  }
#pragma unroll
  for (int c = 0; c < 4; ++c) {
    float v = red[8+c][0] + red[8+c][1] + red[8+c][2] + red[8+c][3];
    float r = rsqrtf(v * (1.0f/256.0f) + 1e-6f);
    k_s[((size_t)s*4 + c)*256 + d] = f2bf(kv[c] * r * kwf);
    v_s[((size_t)s*4 + c)*256 + d] = f2bf(vv[c]);
  }
}

// ---------------- v (s,c,d) -> vT (c,d,s) 64x64 tile transpose ----------------
__global__ __launch_bounds__(256)
void k_vt(const u16* __restrict__ v_s, u16* __restrict__ vT) {
  __shared__ u16 tile[64][72];
  const int s0 = blockIdx.x * 64, d0 = blockIdx.y * 64, c = blockIdx.z;
  const int tid = threadIdx.x;
#pragma unroll
  for (int it = 0; it < 2; ++it) {
    const int u = it * 256 + tid;
    const int r = u >> 3, cc = u & 7;
    const u16* s = &v_s[(((size_t)(s0 + r))*4 + c)*256 + d0 + cc*8];
    ushort4 a = *(const ushort4*)s, b = *(const ushort4*)(s + 4);
    tile[r][cc*8+0]=a.x; tile[r][cc*8+1]=a.y; tile[r][cc*8+2]=a.z; tile[r][cc*8+3]=a.w;
    tile[r][cc*8+4]=b.x; tile[r][cc*8+5]=b.y; tile[r][cc*8+6]=b.z; tile[r][cc*8+7]=b.w;
  }
  __syncthreads();
#pragma unroll
  for (int it = 0; it < 2; ++it) {
    const int u = it * 256 + tid;
    const int dr = u >> 3, sc = u & 7;
    ushort4 a, b;
    a.x = tile[sc*8+0][dr]; a.y = tile[sc*8+1][dr]; a.z = tile[sc*8+2][dr]; a.w = tile[sc*8+3][dr];
    b.x = tile[sc*8+4][dr]; b.y = tile[sc*8+5][dr]; b.z = tile[sc*8+6][dr]; b.w = tile[sc*8+7][dr];
    u16* o = vT + ((size_t)c*256 + d0 + dr)*SEQ + s0 + sc*8;
    *(ushort4*)o = a; *(ushort4*)(o + 4) = b;
  }
}

// ---------------- flash attention, sliding window, softcap ----------------
// Block = 32 queries x 2 heads (GQA pair shares K/V), 4 waves x 16 queries.
// KVBLK=32, double-buffered K+V, ONE barrier per tile (vmcnt+s_barrier).
// Softmax: per-lane partial lrun (no per-tile sum reduce), __any-gated
// defer-max (no per-tile max reduce in the common case), builtin exp2/rcp.
__global__ __launch_bounds__(256)
void k_attn(const u16* __restrict__ q_s, const u16* __restrict__ k_s,
            const u16* __restrict__ vT, const int* __restrict__ idx,
            u16* __restrict__ ao) {
  __shared__ u16 Kt[2][32 * 256];   // 16 KB x2
  __shared__ u16 Vt[2][256 * 32];   // 16 KB x2
  __shared__ u16 Pb[4][16 * 40];    // 5 KB wave-private P
  const int b = blockIdx.x;
  const int c = b & 3, qt = b >> 2;           // c -> XCD affinity (2 XCDs per c)
  const int q0 = qt * 32;
  const int tid = threadIdx.x;
  const int wid = tid >> 6, lane = tid & 63;
  const int l15 = lane & 15, g = lane >> 4;
  const int h = 2*c + (wid >> 1);             // waves 0,1 -> head 2c; 2,3 -> 2c+1
  const int qsub = wid & 1;
  const int qrow = q0 + qsub*16 + l15;
  const int qpos = idx[qrow];

  bf16x8 qf[8];
  const u16* qb = q_s + ((size_t)qrow * 8 + h) * 256;
#pragma unroll
  for (int kk = 0; kk < 8; ++kk) qf[kk] = *(const bf16x8*)(qb + kk*32 + g*8);

  int kbase[8];
#pragma unroll
  for (int kk = 0; kk < 8; ++kk)
    kbase[kk] = l15*256 + (((4*kk + g) ^ (l15 & 7)) * 8);
  const int vbase = l15*32 + ((g ^ ((l15 >> 1) & 3)) * 8);
  u16* KtF = &Kt[0][0];
  u16* VtF = &Vt[0][0];
  u16* Pw  = &Pb[wid][0];

  f32x4 accO[16];
#pragma unroll
  for (int n = 0; n < 16; ++n) accO[n] = (f32x4){0.f,0.f,0.f,0.f};
  float mrun = -50.0f, lrun = 0.0f;           // lrun: per-lane partial

  int t0 = q0 - (WIN - 1); if (t0 < 0) t0 = 0;
  const int kt_lo = t0 >> 5, kt_hi = qt;

  const int srow = tid >> 5;
  const int scl  = (tid & 31) ^ srow;
  const int vdr  = tid >> 2;
  const int vlc  = (tid & 3) ^ ((tid >> 3) & 3);
  const u16* kg = k_s + (size_t)(kt_lo*32 + srow) * 1024 + c*256 + scl*8;
  const u16* vg = vT  + (size_t)c*1048576 + (size_t)vdr*4096 + kt_lo*32 + vlc*8;

  auto stage = [&](int buf) {
#pragma unroll
    for (int i = 0; i < 4; ++i)
      gl_lds16(kg + i*8192,   &Kt[buf][(i*256 + wid*64) * 8]);
#pragma unroll
    for (int i = 0; i < 4; ++i)
      gl_lds16(vg + i*262144, &Vt[buf][(i*256 + wid*64) * 8]);
  };

  stage(0);
  int cur = 0;
  for (int kt = kt_lo; kt <= kt_hi; ++kt) {
    const int k0 = kt * 32;
    sync_vm();                                 // buf[cur] staged (issued 1 tile ago)
    if (kt < kt_hi) { kg += 32768; vg += 32; stage(cur ^ 1); }

    // S^T = K @ Q^T : D[key][q=l15]
    const int kco = cur * 8192;
    f32x4 s0 = (f32x4){0.f,0.f,0.f,0.f}, s1 = (f32x4){0.f,0.f,0.f,0.f};
    __builtin_amdgcn_s_setprio(1);
#pragma unroll
    for (int kk = 0; kk < 8; ++kk) {
      bf16x8 kf0 = *(const bf16x8*)&KtF[kbase[kk] + kco];
      bf16x8 kf1 = *(const bf16x8*)&KtF[kbase[kk] + kco + 4096];
      s0 = __builtin_amdgcn_mfma_f32_16x16x32_bf16(kf0, qf[kk], s0, 0, 0, 0);
      s1 = __builtin_amdgcn_mfma_f32_16x16x32_bf16(kf1, qf[kk], s1, 0, 0, 0);
    }
    __builtin_amdgcn_s_setprio(0);

    // softcap: t = 50 - 100/(1+exp2(x*2*log2e/50))
    float tv[8];
#pragma unroll
    for (int nk = 0; nk < 2; ++nk)
#pragma unroll
      for (int j = 0; j < 4; ++j) {
        float x = (nk == 0) ? s0[j] : s1[j];
        float u = __builtin_amdgcn_exp2f(x * 0.05770780163555854f);
        tv[nk*4+j] = fmaf(-100.0f, __builtin_amdgcn_rcpf(1.0f + u), 50.0f);
      }
    const int dbase = qpos - k0;
    if (kt == kt_hi) {                        // causal edge: key<=qpos
#pragma unroll
      for (int nk = 0; nk < 2; ++nk)
#pragma unroll
        for (int j = 0; j < 4; ++j)
          if (nk*16 + g*4 + j > dbase) tv[nk*4+j] = -1e38f;
    } else if (k0 < q0 - 992) {               // window edge: qpos-key<=1023
#pragma unroll
      for (int nk = 0; nk < 2; ++nk)
#pragma unroll
        for (int j = 0; j < 4; ++j)
          if (dbase - (nk*16 + g*4 + j) > 1023) tv[nk*4+j] = -1e38f;
    }

    float tmax = tv[0];
#pragma unroll
    for (int t = 1; t < 8; ++t) tmax = fmaxf(tmax, tv[t]);
    if (__any(tmax > mrun + 8.0f)) {          // defer-max: reduce only on trigger
      float tq = fmaxf(tmax, __shfl_xor(tmax, 16));
      tq = fmaxf(tq, __shfl_xor(tq, 32));
      const float mnew = fmaxf(mrun, tq);
      const float scale = __builtin_amdgcn_exp2f((mrun - mnew) * 1.442695041f);
      float scj[4];
#pragma unroll
      for (int j = 0; j < 4; ++j) scj[j] = __shfl(scale, g*4 + j);
#pragma unroll
      for (int n = 0; n < 16; ++n) {
        accO[n][0] *= scj[0]; accO[n][1] *= scj[1];
        accO[n][2] *= scj[2]; accO[n][3] *= scj[3];
      }
      lrun *= scale;
      mrun = mnew;
    }
    const float mr2 = mrun * 1.442695041f;
    float p[8];
#pragma unroll
    for (int t = 0; t < 8; ++t) {
      p[t] = __builtin_amdgcn_exp2f(fmaf(tv[t], 1.442695041f, -mr2));
      lrun += p[t];
    }

    // P -> wave-private LDS (bf16), then PV
    uint32_t a0 = cvtpk(p[0], p[1]), a1 = cvtpk(p[2], p[3]);
    uint32_t b0 = cvtpk(p[4], p[5]), b1 = cvtpk(p[6], p[7]);
    { uint2 w = {a0, a1}; *(uint2*)&Pw[l15*40 + g*4]      = w; }
    { uint2 w = {b0, b1}; *(uint2*)&Pw[l15*40 + 16 + g*4] = w; }
    bf16x8 pa = *(const bf16x8*)&Pw[l15*40 + g*8];
    const int vco = cur * 8192;
    __builtin_amdgcn_s_setprio(1);
#pragma unroll
    for (int n = 0; n < 16; ++n) {
      bf16x8 vf = *(const bf16x8*)&VtF[vbase + vco + n*512];
      accO[n] = __builtin_amdgcn_mfma_f32_16x16x32_bf16(pa, vf, accO[n], 0, 0, 0);
    }
    __builtin_amdgcn_s_setprio(0);
    cur ^= 1;
  }

  lrun += __shfl_xor(lrun, 16);
  lrun += __shfl_xor(lrun, 32);
  const float linv = __builtin_amdgcn_rcpf(lrun);
  float lj[4];
#pragma unroll
  for (int j = 0; j < 4; ++j) lj[j] = __shfl(linv, g*4 + j);
#pragma unroll
  for (int n = 0; n < 16; ++n)
#pragma unroll
    for (int j = 0; j < 4; ++j) {
      const int r = q0 + qsub*16 + g*4 + j;
      ao[(size_t)r * HIDN + h*256 + n*16 + l15] = f2bf(accO[n][j] * lj[j]);
    }
}

// ---------------- launch ----------------
extern "C" void kernel_launch(void* const* d_in, const int* in_sizes, int n_in,
                              void* d_out, int out_size, void* d_ws, size_t ws_size,
                              hipStream_t stream) {
  const float* x    = (const float*)d_in[0];
  const float* fcos = (const float*)d_in[1];
  const float* fsin = (const float*)d_in[2];
  const float* waq  = (const float*)d_in[3];
  const float* wak  = (const float*)d_in[4];
  const float* wav  = (const float*)d_in[5];
  const float* wbq  = (const float*)d_in[6];
  const float* wbk  = (const float*)d_in[7];
  const float* wbv  = (const float*)d_in[8];
  const float* wo   = (const float*)d_in[9];
  const float* qnw  = (const float*)d_in[10];
  const float* knw  = (const float*)d_in[11];
  const int*   idx  = (const int*)d_in[16];
  float* out = (float*)d_out;

  char* p = (char*)d_ws;
  u16*  xb   = (u16*)p;                 p += (size_t)SEQ*HIDN*2;
  u16*  wcat = (u16*)p;                 p += (size_t)NPROJP*HIDN*2;
  u16*  wob  = (u16*)p;                 p += (size_t)HIDN*HIDN*2;
  u16*  ypr  = (u16*)p;                 p += (size_t)SEQ*NPROJP*2;     // proj out bf16
  u16*  q_s  = (u16*)p;                 p += (size_t)SEQ*NHEAD*DH*2;
  u16*  k_s  = (u16*)p;                 p += (size_t)SEQ*NKVH*DH*2;
  u16*  v_s  = (u16*)p;                 p += (size_t)SEQ*NKVH*DH*2;
  u16*  vT   = (u16*)p;                 p += (size_t)SEQ*NKVH*DH*2;
  u16*  ao   = (u16*)p;                 p += (size_t)SEQ*HIDN*2;

  k_cvt <<<(SEQ*HIDN/4 + 255)/256, 256, 0, stream>>>(x, xb, SEQ*HIDN/4);
  k_cvt <<<(HIDN*HIDN/4 + 255)/256, 256, 0, stream>>>(wo, wob, HIDN*HIDN/4);
  k_wcat<<<NPROJP, 256, 0, stream>>>(waq, wak, wav, wbq, wbk, wbv, wcat);
  k_gemm_bt<1><<<dim3(NPROJP/128, SEQ/128), 256, 0, stream>>>(xb, wcat, ypr, SEQ, NPROJP, HIDN);
  k_qkv <<<SEQ, 256, 0, stream>>>(ypr, fcos, fsin, qnw, knw, q_s, k_s, v_s);
  k_vt  <<<dim3(SEQ/64, DH/64, NKVH), 256, 0, stream>>>(v_s, vT);
  k_attn<<<dim3(SEQ/32 * NKVH), 256, 0, stream>>>(q_s, k_s, vT, idx, ao);
  k_gemm_bt<0><<<dim3(HIDN/128, SEQ/128), 256, 0, stream>>>(ao, wob, out, SEQ, HIDN, HIDN);
}